// Round 1
// baseline (467.780 us; speedup 1.0000x reference)
//
#include <hip/hip_runtime.h>
#include <math.h>

// Problem constants (from reference)
#define NN 10000      // N_NODES
#define NE 160000     // N_EDGES
// C=16, C2=8, HID=64, NH=2, NG=16, F_IN=64, F_OUT=32
// Only the l=0 irrep channel reaches the output (scal takes cols h*72..h*72+8,
// which come solely from node_out[:,:,0]; Y[:,0]==1). Everything else is dead.

// Workspace layout (floats):
//   x      [10000][16]        @ 0
//   q      [10000][2][16]     @ 160000
//   k      [10000][2][16]     @ 480000
//   dist   [160000]           @ 800000
//   lg     [160000][2]        @ 960000
//   m      [10000][2]         @ 1280000   (init -inf)
//   z      [10000][2]         @ 1300000   (init 0)
//   u      [10000][2][16]     @ 1320000   (init 0)
//   pooled [16][16]           @ 1640000   (init 0)
// total 1640256 floats = 6.56 MB

__device__ __forceinline__ void atomicMaxFloat(float* addr, float val) {
    // sign-split monotonic trick; addr initialized to -inf (0xFF800000)
    if (__float_as_int(val) >= 0) {
        atomicMax((int*)addr, __float_as_int(val));
    } else {
        atomicMin((unsigned int*)addr, __float_as_uint(val));
    }
}

__global__ __launch_bounds__(256) void k_init(float* __restrict__ base, int nMinf, int nTotal) {
    int i = blockIdx.x * 256 + threadIdx.x;
    if (i < nTotal) base[i] = (i < nMinf) ? -INFINITY : 0.0f;
}

// x = nf @ We + be ; q[h] = x @ Wq[h] ; k[h] = x @ Wk[h]
// block = 256 threads = 16 nodes x 16 channels
__global__ __launch_bounds__(256) void k_xqk(const float* __restrict__ nf,
        const float* __restrict__ We, const float* __restrict__ be,
        const float* __restrict__ Wq, const float* __restrict__ Wk,
        float* __restrict__ x, float* __restrict__ q, float* __restrict__ k) {
    __shared__ float sWe[64 * 16];
    __shared__ float sWq[2 * 16 * 16];
    __shared__ float sWk[2 * 16 * 16];
    __shared__ float sNF[16 * 64];
    __shared__ float sX[16 * 16];
    int t = threadIdx.x;
    for (int i = t; i < 1024; i += 256) sWe[i] = We[i];
    for (int i = t; i < 512; i += 256) { sWq[i] = Wq[i]; sWk[i] = Wk[i]; }
    int nodeBase = blockIdx.x * 16;
    for (int i = t; i < 1024; i += 256) {
        int n = nodeBase + (i >> 6);
        sNF[i] = (n < NN) ? nf[n * 64 + (i & 63)] : 0.0f;
    }
    __syncthreads();
    int ln = t >> 4;      // local node 0..15
    int c  = t & 15;      // channel 0..15
    int n  = nodeBase + ln;
    float acc = be[c];
    #pragma unroll 16
    for (int j = 0; j < 64; ++j) acc = fmaf(sNF[ln * 64 + j], sWe[j * 16 + c], acc);
    sX[ln * 16 + c] = acc;
    __syncthreads();
    if (n < NN) {
        x[n * 16 + c] = acc;
        #pragma unroll
        for (int h = 0; h < 2; ++h) {
            float aq = 0.0f, ak = 0.0f;
            #pragma unroll
            for (int j = 0; j < 16; ++j) {
                float xv = sX[ln * 16 + j];
                aq = fmaf(xv, sWq[(h * 16 + j) * 16 + c], aq);
                ak = fmaf(xv, sWk[(h * 16 + j) * 16 + c], ak);
            }
            q[(n * 2 + h) * 16 + c] = aq;
            k[(n * 2 + h) * 16 + c] = ak;
        }
    }
}

// per-edge: dist, logits, atomic segment-max over tgt
__global__ __launch_bounds__(256) void k_edge1(const float* __restrict__ pos,
        const int* __restrict__ ei,
        const float* __restrict__ q, const float* __restrict__ k,
        const float* __restrict__ W1, const float* __restrict__ b1, const float* __restrict__ Wa,
        float* __restrict__ dist, float* __restrict__ lg, float* __restrict__ m) {
    __shared__ float sW1[128], sB1[128], sWa[128];
    int t0 = threadIdx.x;
    if (t0 < 128) { sW1[t0] = W1[t0]; sB1[t0] = b1[t0]; sWa[t0] = Wa[t0]; }
    __syncthreads();
    int e = blockIdx.x * 256 + t0;
    if (e >= NE) return;
    int s = ei[e], t = ei[NE + e];
    float dx = pos[t * 3 + 0] - pos[s * 3 + 0];
    float dy = pos[t * 3 + 1] - pos[s * 3 + 1];
    float dz = pos[t * 3 + 2] - pos[s * 3 + 2];
    float d = sqrtf(dx * dx + dy * dy + dz * dz);
    dist[e] = d;
    float fh[2];
    fh[0] = d;
    fh[1] = 1.0f / (d * d);
    const float4* qt = (const float4*)(q + (size_t)t * 32);
    const float4* ks = (const float4*)(k + (size_t)s * 32);
    #pragma unroll
    for (int h = 0; h < 2; ++h) {
        float4 a0 = qt[h * 4 + 0], a1 = qt[h * 4 + 1], a2 = qt[h * 4 + 2], a3 = qt[h * 4 + 3];
        float4 b0 = ks[h * 4 + 0], c1 = ks[h * 4 + 1], c2 = ks[h * 4 + 2], c3 = ks[h * 4 + 3];
        float dot = a0.x * b0.x + a0.y * b0.y + a0.z * b0.z + a0.w * b0.w
                  + a1.x * c1.x + a1.y * c1.y + a1.z * c1.z + a1.w * c1.w
                  + a2.x * c2.x + a2.y * c2.y + a2.z * c2.z + a2.w * c2.w
                  + a3.x * c3.x + a3.y * c3.y + a3.z * c3.z + a3.w * c3.w;
        float f = fh[h];
        float att = 0.0f;
        #pragma unroll 8
        for (int j = 0; j < 64; ++j) {
            float hj = fmaxf(fmaf(f, sW1[h * 64 + j], sB1[h * 64 + j]), 0.0f);
            att = fmaf(hj, sWa[h * 64 + j], att);
        }
        float L = fmaf(dot, 0.25f, att);
        lg[e * 2 + h] = L;
        atomicMaxFloat(&m[t * 2 + h], L);
    }
}

// per-edge: w = exp(logit - m[tgt]); wv0 = relu(f*W1+b1) @ Wv[:, ::3];
// u[tgt][h][c] += w * wv0[c] * x[src][c]; z[tgt][h] += w
__global__ __launch_bounds__(256) void k_edge2(const int* __restrict__ ei,
        const float* __restrict__ dist, const float* __restrict__ lg, const float* __restrict__ m,
        const float* __restrict__ x,
        const float* __restrict__ W1, const float* __restrict__ b1, const float* __restrict__ Wv,
        float* __restrict__ z, float* __restrict__ u) {
    __shared__ float sV[2 * 64 * 16];   // compacted Wv[h][j][3c], [h][j][c], 8 KB
    __shared__ float sW1[128], sB1[128];
    int t0 = threadIdx.x;
    for (int i = t0; i < 2048; i += 256) {
        int h = i >> 10, j = (i >> 4) & 63, c = i & 15;
        sV[i] = Wv[(h * 64 + j) * 48 + 3 * c];
    }
    if (t0 < 128) { sW1[t0] = W1[t0]; sB1[t0] = b1[t0]; }
    __syncthreads();
    int e = blockIdx.x * 256 + t0;
    if (e >= NE) return;
    int s = ei[e], t = ei[NE + e];
    float d = dist[e];
    float2 Lg = *(const float2*)(lg + e * 2);
    float2 Mg = *(const float2*)(m + (size_t)t * 2);
    const float4* xp = (const float4*)(x + (size_t)s * 16);
    float4 xs0 = xp[0], xs1 = xp[1], xs2 = xp[2], xs3 = xp[3];
    float xf[16] = { xs0.x, xs0.y, xs0.z, xs0.w, xs1.x, xs1.y, xs1.z, xs1.w,
                     xs2.x, xs2.y, xs2.z, xs2.w, xs3.x, xs3.y, xs3.z, xs3.w };
    float fv[2] = { d, 1.0f / (d * d) };
    float Lv[2] = { Lg.x, Lg.y };
    float Mv[2] = { Mg.x, Mg.y };
    #pragma unroll
    for (int h = 0; h < 2; ++h) {
        float w = __expf(Lv[h] - Mv[h]);
        atomicAdd(&z[t * 2 + h], w);
        float acc[16];
        #pragma unroll
        for (int c = 0; c < 16; ++c) acc[c] = 0.0f;
        const float4* vp = (const float4*)(sV + h * 1024);
        float f = fv[h];
        for (int j = 0; j < 64; ++j) {
            float hj = fmaxf(fmaf(f, sW1[h * 64 + j], sB1[h * 64 + j]), 0.0f);
            float4 v0 = vp[j * 4 + 0], v1 = vp[j * 4 + 1], v2 = vp[j * 4 + 2], v3 = vp[j * 4 + 3];
            acc[0]  = fmaf(hj, v0.x, acc[0]);  acc[1]  = fmaf(hj, v0.y, acc[1]);
            acc[2]  = fmaf(hj, v0.z, acc[2]);  acc[3]  = fmaf(hj, v0.w, acc[3]);
            acc[4]  = fmaf(hj, v1.x, acc[4]);  acc[5]  = fmaf(hj, v1.y, acc[5]);
            acc[6]  = fmaf(hj, v1.z, acc[6]);  acc[7]  = fmaf(hj, v1.w, acc[7]);
            acc[8]  = fmaf(hj, v2.x, acc[8]);  acc[9]  = fmaf(hj, v2.y, acc[9]);
            acc[10] = fmaf(hj, v2.z, acc[10]); acc[11] = fmaf(hj, v2.w, acc[11]);
            acc[12] = fmaf(hj, v3.x, acc[12]); acc[13] = fmaf(hj, v3.y, acc[13]);
            acc[14] = fmaf(hj, v3.z, acc[14]); acc[15] = fmaf(hj, v3.w, acc[15]);
        }
        float* ut = u + (size_t)(t * 2 + h) * 16;
        #pragma unroll
        for (int c = 0; c < 16; ++c) atomicAdd(&ut[c], (w * acc[c]) * xf[c]);
    }
}

// per (node, head, o): part0 = (u/z) . Wo[h][0][:, o]; pool by batch group
__global__ __launch_bounds__(256) void k_node(const float* __restrict__ u, const float* __restrict__ z,
        const float* __restrict__ Wo, const int* __restrict__ batch,
        float* __restrict__ pooled) {
    int i = blockIdx.x * 256 + threadIdx.x;
    if (i >= NN * 16) return;
    int n = i >> 4, ho = i & 15, h = ho >> 3, o = ho & 7;
    float zz = z[n * 2 + h];
    if (!(zz > 0.0f)) return;   // node with no incoming edges contributes 0
    float inv = 1.0f / zz;
    const float* un = u + (size_t)(n * 2 + h) * 16;
    float acc = 0.0f;
    #pragma unroll
    for (int c = 0; c < 16; ++c) acc = fmaf(un[c], Wo[((h * 3 + 0) * 16 + c) * 8 + o], acc);
    atomicAdd(&pooled[batch[n] * 16 + ho], acc * inv);
}

// out[g][f] = pooled[g][:] . Wproj[:, f] + bproj[f]   (16x16x32)
__global__ __launch_bounds__(512) void k_final(const float* __restrict__ pooled,
        const float* __restrict__ Wproj, const float* __restrict__ bproj,
        float* __restrict__ out) {
    int t = threadIdx.x;          // 512 = 16 groups x 32 outputs
    int g = t >> 5, fo = t & 31;
    float acc = bproj[fo];
    #pragma unroll
    for (int j = 0; j < 16; ++j) acc = fmaf(pooled[g * 16 + j], Wproj[j * 32 + fo], acc);
    out[g * 32 + fo] = acc;
}

extern "C" void kernel_launch(void* const* d_in, const int* in_sizes, int n_in,
                              void* d_out, int out_size, void* d_ws, size_t ws_size,
                              hipStream_t stream) {
    const float* nf    = (const float*)d_in[0];
    const float* pos   = (const float*)d_in[1];
    const float* We    = (const float*)d_in[2];
    const float* be    = (const float*)d_in[3];
    const float* Wq    = (const float*)d_in[4];
    const float* Wk    = (const float*)d_in[5];
    const float* W1    = (const float*)d_in[6];
    const float* b1    = (const float*)d_in[7];
    const float* Wa    = (const float*)d_in[8];
    const float* Wv    = (const float*)d_in[9];
    const float* Wo    = (const float*)d_in[10];
    const float* Wproj = (const float*)d_in[11];
    const float* bproj = (const float*)d_in[12];
    const int*   ei    = (const int*)d_in[13];
    const int*   batch = (const int*)d_in[14];
    float* out = (float*)d_out;

    float* ws     = (float*)d_ws;
    float* x      = ws;
    float* q      = x + 160000;
    float* k      = q + 320000;
    float* dist   = k + 320000;
    float* lg     = dist + 160000;
    float* m      = lg + 320000;
    float* z      = m + 20000;      // unused name at launch; contiguous with m
    float* u      = z + 20000;
    float* pooled = u + 320000;
    (void)z; (void)in_sizes; (void)n_in; (void)out_size; (void)ws_size;

    // init m=-inf (20000 floats), then z,u,pooled = 0 (340256 floats); contiguous
    hipLaunchKernelGGL(k_init,  dim3(1408), dim3(256), 0, stream, m, 20000, 360256);
    hipLaunchKernelGGL(k_xqk,   dim3(625),  dim3(256), 0, stream, nf, We, be, Wq, Wk, x, q, k);
    hipLaunchKernelGGL(k_edge1, dim3(625),  dim3(256), 0, stream, pos, ei, q, k, W1, b1, Wa, dist, lg, m);
    hipLaunchKernelGGL(k_edge2, dim3(625),  dim3(256), 0, stream, ei, dist, lg, m, x, W1, b1, Wv,
                       m + 20000 /*z*/, u);
    hipLaunchKernelGGL(k_node,  dim3(625),  dim3(256), 0, stream, u, m + 20000 /*z*/, Wo, batch, pooled);
    hipLaunchKernelGGL(k_final, dim3(1),    dim3(512), 0, stream, pooled, Wproj, bproj, out);
}

// Round 2
// 175.322 us; speedup vs baseline: 2.6681x; 2.6681x over previous
//
#include <hip/hip_runtime.h>
#include <math.h>

#define NN 10000
#define NE 160000
// Only the l=0 irrep reaches the output (scal takes cols h*72..h*72+8 of pooled,
// which come solely from node_out[:,:,0]; Y[:,0]==1). l=1/l=2 paths are dead.
//
// Round 2: scatter-atomics -> CSR gather. rocprof showed k_edge2 WRITE_SIZE
// = 5.44M atomics x 32B = 174 MB HBM write-through; atomics were 100% of time.
//
// Workspace (floats then ints):
//   x      [10000][16]       @ 0
//   q      [10000][2][16]    @ 160000
//   k      [10000][2][16]    @ 480000
//   lg     [160000][2]       @ 800000
//   wv0    [160000][2][16]   @ 1120000
//   feat   [10000][16]       @ 6240000
//   pooled [16][16]          @ 6400000
//   deg    int[10000]        @ 6400256   (pooled..deg zeroed together: 10256 dwords)
//   row    int[10001]
//   cur    int[10000]
//   eid    int[160000]
// total ~26.4 MB

__global__ __launch_bounds__(256) void k_zero(int* __restrict__ p, int n) {
    int i = blockIdx.x * 256 + threadIdx.x;
    if (i < n) p[i] = 0;
}

__global__ __launch_bounds__(256) void k_hist(const int* __restrict__ ei, int* __restrict__ deg) {
    int e = blockIdx.x * 256 + threadIdx.x;
    if (e < NE) atomicAdd(&deg[ei[NE + e]], 1);
}

// exclusive scan of deg[10000] -> row[10001]; copy to cur
__global__ __launch_bounds__(1024) void k_scan(const int* __restrict__ deg,
        int* __restrict__ row, int* __restrict__ cur) {
    __shared__ int sP[1024];
    int t = threadIdx.x;
    int base = t * 10;
    int loc[10];
    int sum = 0;
    #pragma unroll
    for (int j = 0; j < 10; ++j) {
        int v = (base + j < NN) ? deg[base + j] : 0;
        loc[j] = sum; sum += v;
    }
    sP[t] = sum;
    __syncthreads();
    for (int off = 1; off < 1024; off <<= 1) {
        int v = (t >= off) ? sP[t - off] : 0;
        __syncthreads();
        sP[t] += v;
        __syncthreads();
    }
    int start = sP[t] - sum;   // exclusive prefix of this thread's chunk
    #pragma unroll
    for (int j = 0; j < 10; ++j) {
        if (base + j < NN) { int r = start + loc[j]; row[base + j] = r; cur[base + j] = r; }
    }
    if (t == 1023) row[NN] = sP[1023];
}

__global__ __launch_bounds__(256) void k_scatter(const int* __restrict__ ei,
        int* __restrict__ cur, int* __restrict__ eid) {
    int e = blockIdx.x * 256 + threadIdx.x;
    if (e < NE) {
        int p = atomicAdd(&cur[ei[NE + e]], 1);
        eid[p] = e;
    }
}

// x = nf @ We + be ; q[h] = x @ Wq[h] ; k[h] = x @ Wk[h]
__global__ __launch_bounds__(256) void k_xqk(const float* __restrict__ nf,
        const float* __restrict__ We, const float* __restrict__ be,
        const float* __restrict__ Wq, const float* __restrict__ Wk,
        float* __restrict__ x, float* __restrict__ q, float* __restrict__ k) {
    __shared__ float sWe[64 * 16];
    __shared__ float sWq[2 * 16 * 16];
    __shared__ float sWk[2 * 16 * 16];
    __shared__ float sNF[16 * 64];
    __shared__ float sX[16 * 16];
    int t = threadIdx.x;
    for (int i = t; i < 1024; i += 256) sWe[i] = We[i];
    for (int i = t; i < 512; i += 256) { sWq[i] = Wq[i]; sWk[i] = Wk[i]; }
    int nodeBase = blockIdx.x * 16;
    for (int i = t; i < 1024; i += 256) {
        int n = nodeBase + (i >> 6);
        sNF[i] = (n < NN) ? nf[n * 64 + (i & 63)] : 0.0f;
    }
    __syncthreads();
    int ln = t >> 4, c = t & 15;
    int n = nodeBase + ln;
    float acc = be[c];
    #pragma unroll 16
    for (int j = 0; j < 64; ++j) acc = fmaf(sNF[ln * 64 + j], sWe[j * 16 + c], acc);
    sX[ln * 16 + c] = acc;
    __syncthreads();
    if (n < NN) {
        x[n * 16 + c] = acc;
        #pragma unroll
        for (int h = 0; h < 2; ++h) {
            float aq = 0.0f, ak = 0.0f;
            #pragma unroll
            for (int j = 0; j < 16; ++j) {
                float xv = sX[ln * 16 + j];
                aq = fmaf(xv, sWq[(h * 16 + j) * 16 + c], aq);
                ak = fmaf(xv, sWk[(h * 16 + j) * 16 + c], ak);
            }
            q[(n * 2 + h) * 16 + c] = aq;
            k[(n * 2 + h) * 16 + c] = ak;
        }
    }
}

// per-edge, no atomics: lg[e][h] = q[t].k[s]/4 + relu(f*W1+b1).Wa
//                       wv0[e][h][c] = relu(f*W1+b1) . Wv[:,3c]
__global__ __launch_bounds__(256) void k_edgeA(const float* __restrict__ pos,
        const int* __restrict__ ei,
        const float* __restrict__ q, const float* __restrict__ k,
        const float* __restrict__ W1, const float* __restrict__ b1,
        const float* __restrict__ Wa, const float* __restrict__ Wv,
        float* __restrict__ lg, float* __restrict__ wv0) {
    __shared__ float sW1[128], sB1[128], sWa[128];
    __shared__ float sV[2048];   // [h][j][c] compacted Wv[:, ::3]
    int t0 = threadIdx.x;
    if (t0 < 128) { sW1[t0] = W1[t0]; sB1[t0] = b1[t0]; sWa[t0] = Wa[t0]; }
    for (int i = t0; i < 2048; i += 256) {
        int h = i >> 10, j = (i >> 4) & 63, c = i & 15;
        sV[i] = Wv[(h * 64 + j) * 48 + 3 * c];
    }
    __syncthreads();
    int e = blockIdx.x * 256 + t0;
    if (e >= NE) return;
    int s = ei[e], t = ei[NE + e];
    float dx = pos[t * 3 + 0] - pos[s * 3 + 0];
    float dy = pos[t * 3 + 1] - pos[s * 3 + 1];
    float dz = pos[t * 3 + 2] - pos[s * 3 + 2];
    float d = sqrtf(dx * dx + dy * dy + dz * dz);
    float fh[2] = { d, 1.0f / (d * d) };
    const float4* qt = (const float4*)(q + (size_t)t * 32);
    const float4* ks = (const float4*)(k + (size_t)s * 32);
    #pragma unroll
    for (int h = 0; h < 2; ++h) {
        float4 a0 = qt[h * 4 + 0], a1 = qt[h * 4 + 1], a2 = qt[h * 4 + 2], a3 = qt[h * 4 + 3];
        float4 b0 = ks[h * 4 + 0], c1 = ks[h * 4 + 1], c2 = ks[h * 4 + 2], c3 = ks[h * 4 + 3];
        float dot = a0.x * b0.x + a0.y * b0.y + a0.z * b0.z + a0.w * b0.w
                  + a1.x * c1.x + a1.y * c1.y + a1.z * c1.z + a1.w * c1.w
                  + a2.x * c2.x + a2.y * c2.y + a2.z * c2.z + a2.w * c2.w
                  + a3.x * c3.x + a3.y * c3.y + a3.z * c3.z + a3.w * c3.w;
        float f = fh[h];
        float att = 0.0f;
        float acc[16];
        #pragma unroll
        for (int c = 0; c < 16; ++c) acc[c] = 0.0f;
        const float4* vp = (const float4*)(sV + h * 1024);
        for (int j = 0; j < 64; ++j) {
            float hj = fmaxf(fmaf(f, sW1[h * 64 + j], sB1[h * 64 + j]), 0.0f);
            att = fmaf(hj, sWa[h * 64 + j], att);
            float4 v0 = vp[j * 4 + 0], v1 = vp[j * 4 + 1], v2 = vp[j * 4 + 2], v3 = vp[j * 4 + 3];
            acc[0]  = fmaf(hj, v0.x, acc[0]);  acc[1]  = fmaf(hj, v0.y, acc[1]);
            acc[2]  = fmaf(hj, v0.z, acc[2]);  acc[3]  = fmaf(hj, v0.w, acc[3]);
            acc[4]  = fmaf(hj, v1.x, acc[4]);  acc[5]  = fmaf(hj, v1.y, acc[5]);
            acc[6]  = fmaf(hj, v1.z, acc[6]);  acc[7]  = fmaf(hj, v1.w, acc[7]);
            acc[8]  = fmaf(hj, v2.x, acc[8]);  acc[9]  = fmaf(hj, v2.y, acc[9]);
            acc[10] = fmaf(hj, v2.z, acc[10]); acc[11] = fmaf(hj, v2.w, acc[11]);
            acc[12] = fmaf(hj, v3.x, acc[12]); acc[13] = fmaf(hj, v3.y, acc[13]);
            acc[14] = fmaf(hj, v3.z, acc[14]); acc[15] = fmaf(hj, v3.w, acc[15]);
        }
        lg[e * 2 + h] = fmaf(dot, 0.25f, att);
        float4* op = (float4*)(wv0 + ((size_t)e * 2 + h) * 16);
        op[0] = make_float4(acc[0], acc[1], acc[2], acc[3]);
        op[1] = make_float4(acc[4], acc[5], acc[6], acc[7]);
        op[2] = make_float4(acc[8], acc[9], acc[10], acc[11]);
        op[3] = make_float4(acc[12], acc[13], acc[14], acc[15]);
    }
}

// one wave per (node, head): gather incoming edges, online softmax in registers,
// apply Wo[h][0] (16x8), write feat[n][h*8+o]. Zero global atomics.
__global__ __launch_bounds__(256) void k_gather(const int* __restrict__ ei,
        const int* __restrict__ row, const int* __restrict__ eid,
        const float* __restrict__ lg, const float* __restrict__ wv0,
        const float* __restrict__ x, const float* __restrict__ Wo,
        float* __restrict__ feat) {
    __shared__ float sWo[256];     // [h][c][o] = Wo[h*384 + c*8 + o]
    __shared__ float sUn[4][16];
    int t0 = threadIdx.x;
    sWo[t0] = Wo[(t0 >> 7) * 384 + (t0 & 127)];
    __syncthreads();
    int wave = (blockIdx.x * 256 + t0) >> 6;   // == pair id, grid sized exactly
    int lane = t0 & 63;
    int n = wave >> 1, h = wave & 1;
    int rs = row[n], deg = row[n + 1] - rs;
    // pass 1: wave max of logits
    float m = -INFINITY;
    for (int i = lane; i < deg; i += 64) {
        int e = eid[rs + i];
        m = fmaxf(m, lg[e * 2 + h]);
    }
    #pragma unroll
    for (int off = 32; off >= 1; off >>= 1) m = fmaxf(m, __shfl_xor(m, off, 64));
    // pass 2: (le,c) lanes accumulate u[c], z
    int le = lane >> 4, c = lane & 15;
    float z = 0.0f, u = 0.0f;
    for (int i = le; i < deg; i += 4) {
        int e = eid[rs + i];
        float w = __expf(lg[e * 2 + h] - m);
        int s = ei[e];
        float wv = wv0[((size_t)e * 2 + h) * 16 + c];
        u = fmaf(w * wv, x[s * 16 + c], u);
        z += w;
    }
    u += __shfl_xor(u, 16, 64); u += __shfl_xor(u, 32, 64);
    z += __shfl_xor(z, 16, 64); z += __shfl_xor(z, 32, 64);
    float un = (z > 0.0f) ? u / z : 0.0f;
    int wslot = t0 >> 6;
    if (lane < 16) sUn[wslot][lane] = un;
    // wave-internal LDS round-trip: lockstep within wave, compiler waits lgkmcnt
    if (lane < 8) {
        float o_acc = 0.0f;
        #pragma unroll
        for (int cc = 0; cc < 16; ++cc)
            o_acc = fmaf(sUn[wslot][cc], sWo[h * 128 + cc * 8 + lane], o_acc);
        feat[n * 16 + h * 8 + lane] = o_acc;
    }
}

// pooled[g][hc] += feat[n][hc] for batch[n]==g; LDS pre-aggregation, 40 blocks
__global__ __launch_bounds__(256) void k_pool(const float* __restrict__ feat,
        const int* __restrict__ batch, float* __restrict__ pooled) {
    __shared__ float sP[256];
    int t = threadIdx.x;
    sP[t] = 0.0f;
    __syncthreads();
    for (int i = blockIdx.x * 256 + t; i < NN * 16; i += 40 * 256) {
        int n = i >> 4, c = i & 15;
        atomicAdd(&sP[batch[n] * 16 + c], feat[i]);
    }
    __syncthreads();
    atomicAdd(&pooled[t], sP[t]);
}

__global__ __launch_bounds__(512) void k_final(const float* __restrict__ pooled,
        const float* __restrict__ Wproj, const float* __restrict__ bproj,
        float* __restrict__ out) {
    int t = threadIdx.x;
    int g = t >> 5, fo = t & 31;
    float acc = bproj[fo];
    #pragma unroll
    for (int j = 0; j < 16; ++j) acc = fmaf(pooled[g * 16 + j], Wproj[j * 32 + fo], acc);
    out[g * 32 + fo] = acc;
}

extern "C" void kernel_launch(void* const* d_in, const int* in_sizes, int n_in,
                              void* d_out, int out_size, void* d_ws, size_t ws_size,
                              hipStream_t stream) {
    const float* nf    = (const float*)d_in[0];
    const float* pos   = (const float*)d_in[1];
    const float* We    = (const float*)d_in[2];
    const float* be    = (const float*)d_in[3];
    const float* Wq    = (const float*)d_in[4];
    const float* Wk    = (const float*)d_in[5];
    const float* W1    = (const float*)d_in[6];
    const float* b1    = (const float*)d_in[7];
    const float* Wa    = (const float*)d_in[8];
    const float* Wv    = (const float*)d_in[9];
    const float* Wo    = (const float*)d_in[10];
    const float* Wproj = (const float*)d_in[11];
    const float* bproj = (const float*)d_in[12];
    const int*   ei    = (const int*)d_in[13];
    const int*   batch = (const int*)d_in[14];
    float* out = (float*)d_out;
    (void)in_sizes; (void)n_in; (void)out_size; (void)ws_size;

    float* ws     = (float*)d_ws;
    float* x      = ws;                  // 160000
    float* q      = x + 160000;          // 320000
    float* k      = q + 320000;          // 320000
    float* lg     = k + 320000;          // 320000
    float* wv0    = lg + 320000;         // 5120000
    float* feat   = wv0 + 5120000;       // 160000
    float* pooled = feat + 160000;       // 256
    int*   deg    = (int*)(pooled + 256);
    int*   row    = deg + 10000;
    int*   cur    = row + 10001;
    int*   eid    = cur + 10000;

    // zero pooled(256f) + deg(10000i) in one shot (contiguous)
    hipLaunchKernelGGL(k_zero,    dim3(41),   dim3(256), 0, stream, (int*)pooled, 10256);
    hipLaunchKernelGGL(k_hist,    dim3(625),  dim3(256), 0, stream, ei, deg);
    hipLaunchKernelGGL(k_scan,    dim3(1),    dim3(1024), 0, stream, deg, row, cur);
    hipLaunchKernelGGL(k_scatter, dim3(625),  dim3(256), 0, stream, ei, cur, eid);
    hipLaunchKernelGGL(k_xqk,     dim3(625),  dim3(256), 0, stream, nf, We, be, Wq, Wk, x, q, k);
    hipLaunchKernelGGL(k_edgeA,   dim3(625),  dim3(256), 0, stream, pos, ei, q, k, W1, b1, Wa, Wv, lg, wv0);
    hipLaunchKernelGGL(k_gather,  dim3(5000), dim3(256), 0, stream, ei, row, eid, lg, wv0, x, Wo, feat);
    hipLaunchKernelGGL(k_pool,    dim3(40),   dim3(256), 0, stream, feat, batch, pooled);
    hipLaunchKernelGGL(k_final,   dim3(1),    dim3(512), 0, stream, pooled, Wproj, bproj, out);
}